// Round 3
// baseline (377.868 us; speedup 1.0000x reference)
//
#include <hip/hip_runtime.h>
#include <hip/hip_bf16.h>

typedef unsigned int uint_t;
typedef __attribute__((ext_vector_type(8))) short bf16x8;   // MFMA A/B frag (4 VGPRs)
typedef __attribute__((ext_vector_type(4))) float f32x4;    // MFMA C/D frag

#define NPTS 50000
#define DIM  64
#define KNB  16
#define GPW  8                  // points per wave (one group per wave)
#define NGROUPS (NPTS / GPW)    // 6250
#define WPB  4                  // waves per block
#define NBLOCKS ((NGROUPS + WPB - 1) / WPB)

// ws layout in 32-bit words: frag images are [f*256 + lane*4 + w]
#define FR_WA    0       // Wa frag image (8 frags)
#define FR_PSIG  2048    // -(Wpsi@Wg) frag image
#define FR_WG    4096    // Wg, rows sigma-permuted, frag image
#define FR_PHIG  6144    // (Wphi@Wg) frag image
#define WC4      8192    // 64 x float4 (wcx,wcy,wcz,wbc)
#define GB       8448    // (bphi-bpsi)@Wg + bg
#define BA       8512    // b_alpha

__device__ __forceinline__ uint_t pk(float a, float b) {
    union { __hip_bfloat162 h; uint_t u; } cv;
    cv.h = __float22bfloat162_rn(float2{a, b});
    return cv.u;
}

union Frag { uint_t u[4]; bf16x8 s; uint4 v; };

// sigma: row-permutation of Wg so that the utr writer's in-lane (nt0,nt1)/(nt2,nt3)
// pairs land as the reader's consecutive A-frag k-dim pairs.
__device__ __forceinline__ int sigma(int k) {
    int t = k >> 1;
    return (t & 15) + 32 * (t >> 4) + 16 * (k & 1);
}

__global__ void pt_prep(const float* __restrict__ Wphi, const float* __restrict__ bphi,
                        const float* __restrict__ Wpsi, const float* __restrict__ bpsi,
                        const float* __restrict__ Wa,   const float* __restrict__ ba,
                        const float* __restrict__ Wg,   const float* __restrict__ bg,
                        const float* __restrict__ Wd1,  const float* __restrict__ bd1,
                        const float* __restrict__ Wd2,  const float* __restrict__ bd2,
                        float* __restrict__ ws) {
    int b = blockIdx.x, t = threadIdx.x;
    uint_t* wsu = (uint_t*)ws;
    if (b < 32) {
        int gid  = b * 256 + t;             // [0, 8192)
        int img  = gid >> 11;               // 0..3
        int rem  = gid & 2047;
        int f    = rem >> 8;                // 0..7  (nt = f>>1, s = f&1)
        int lane = (rem >> 2) & 63;
        int w    = rem & 3;
        int k0   = (f & 1) * 32 + (lane >> 4) * 8 + 2 * w;
        int k1   = k0 + 1;
        int n    = (f >> 1) * 16 + (lane & 15);
        float v0, v1;
        if (img == 0) {                     // Wa
            v0 = Wa[k0 * 64 + n]; v1 = Wa[k1 * 64 + n];
            wsu[FR_WA + rem] = pk(v0, v1);
        } else if (img == 1) {              // -(Wpsi@Wg)
            float a0 = 0.f, a1 = 0.f;
            for (int c = 0; c < 64; ++c) {
                float wgc = Wg[c * 64 + n];
                a0 += Wpsi[k0 * 64 + c] * wgc;
                a1 += Wpsi[k1 * 64 + c] * wgc;
            }
            wsu[FR_PSIG + rem] = pk(-a0, -a1);
        } else if (img == 2) {              // Wg sigma-row-permuted
            v0 = Wg[sigma(k0) * 64 + n]; v1 = Wg[sigma(k1) * 64 + n];
            wsu[FR_WG + rem] = pk(v0, v1);
        } else {                            // Wphi@Wg
            float a0 = 0.f, a1 = 0.f;
            for (int c = 0; c < 64; ++c) {
                float wgc = Wg[c * 64 + n];
                a0 += Wphi[k0 * 64 + c] * wgc;
                a1 += Wphi[k1 * 64 + c] * wgc;
            }
            wsu[FR_PHIG + rem] = pk(a0, a1);
        }
    } else if (t < 64) {
        // wc4: folded W_d1@W_d2 (+ folded bias), gb, ba
        float wx = 0.f, wy = 0.f, wz = 0.f;
        for (int m = 0; m < 64; ++m) {
            float w2 = Wd2[m * 64 + t];
            wx += Wd1[m] * w2;
            wy += Wd1[64 + m] * w2;
            wz += Wd1[128 + m] * w2;
        }
        float wb = bd2[t];
        for (int m = 0; m < 64; ++m) wb += bd1[m] * Wd2[m * 64 + t];
        ws[WC4 + t * 4 + 0] = wx;
        ws[WC4 + t * 4 + 1] = wy;
        ws[WC4 + t * 4 + 2] = wz;
        ws[WC4 + t * 4 + 3] = wb;
        float g = bg[t];
        for (int c = 0; c < 64; ++c) g += (bphi[c] - bpsi[c]) * Wg[c * 64 + t];
        ws[GB + t] = g;
        ws[BA + t] = ba[t];
    }
}

#define MFMA(A, B, C) __builtin_amdgcn_mfma_f32_16x16x32_bf16((A), (B), (C), 0, 0, 0)

// per-wave LDS word layout:
// phig 520 | utr 544 (also pfeat bounce scratch in preamble) | dxyz 128 | pxyz 32
// | obuf 512 | nf 2 slots x 1024 (double-buffered point features)
#define O_PHIG 0
#define O_UTR  520
#define O_DXY  1064
#define O_PXY  1192
#define O_OBUF 1224
#define O_NF   1736
#define WAREA  (O_NF + 2 * 1024)   // 3784 words = 15136 B/wave; 60544 B/block (2 blocks/CU)

__global__ __launch_bounds__(256, 2)
void pt_main(const float* __restrict__ pxyz, const float* __restrict__ pfeat,
             const float* __restrict__ nxyz, const float* __restrict__ nfeat,
             const float* __restrict__ ws,   float* __restrict__ out) {
    __shared__ float lds[WPB][WAREA];

    const int t    = threadIdx.x;
    const int wv   = t >> 6;
    const int lane = t & 63;
    const int c16  = lane & 15;
    const int quad = lane >> 4;

    const int g = blockIdx.x * WPB + wv;
    if (g >= NGROUPS) return;            // no block-level barriers anywhere

    float*  W      = lds[wv];
    float*  phig_s = W + O_PHIG;
    uint_t* utr    = (uint_t*)(W + O_UTR);
    float*  dxyz   = W + O_DXY;
    float*  pxyz_s = W + O_PXY;
    float*  obuf   = W + O_OBUF;
    float*  nfl    = W + O_NF;

    const int g0 = g * GPW;
    const int k3 = lane / 3, c3 = lane - k3 * 3;   // lane<48: (neighbor, component)

    // per-lane rotated source offsets: instruction j's 64 lanes densely cover
    // bytes [j*1024,(j+1)*1024) of the point's 4KB row-block (every 32B sector
    // fully covered WITHIN one instruction -> no sector over-fetch).
    int soff[4];
    #pragma unroll
    for (int j = 0; j < 4; ++j) {
        int row = j * 4 + quad;                       // neighbor row this lane covers
        soff[j] = row * 256 + (((c16 - row) & 15) << 4);
    }

    const char* nfbase = (const char*)nfeat + (size_t)g0 * 4096;

    // reg-stage point 0 (dense loads), issued first so latency hides under preamble
    float4 x[4];
    #pragma unroll
    for (int j = 0; j < 4; ++j)
        x[j] = *(const float4*)(nfbase + soff[j]);

    // ---- persistent weights in registers (zero-latency MFMA operands) ----
    const uint4* fr = (const uint4*)ws;       // frag uint4 index = IMG/4 + f*64 + lane
    Frag wa[8], wpsig[8], wg[8];
    #pragma unroll
    for (int f = 0; f < 8; ++f) {
        wa[f].v    = fr[        f * 64 + lane];
        wpsig[f].v = fr[ 512 +  f * 64 + lane];
        wg[f].v    = fr[1024 +  f * 64 + lane];
    }
    float4 wc[4];
    float ba_r[4], gbr[4];
    #pragma unroll
    for (int nt = 0; nt < 4; ++nt) {
        int d = nt * 16 + c16;
        wc[nt]   = ((const float4*)(ws + WC4))[d];
        ba_r[nt] = ws[BA + d];
        gbr[nt]  = ws[GB + d];
    }

    if (lane < 24) pxyz_s[lane] = pxyz[g0 * 3 + lane];
    float nv0 = (lane < 48) ? nxyz[(size_t)g0 * 48 + lane] : 0.f;
    if (lane < 48) dxyz[k3 * 4 + c3] = pxyz_s[c3] - nv0;   // point 0, buf 0

    // pfeat: dense load -> LDS bounce (utr region as scratch), then frag reads.
    {
        float4* scr4 = (float4*)(W + O_UTR);
        const float4* pfg4 = (const float4*)(pfeat + (size_t)g0 * 64);
        if (lane < 32) {
            #pragma unroll
            for (int j = 0; j < 4; ++j)
                scr4[j * 32 + lane] = pfg4[j * 32 + lane];
        }
        float4 x0{}, x1{}, x2{}, x3{};
        if (c16 < 8) {                      // row c16, chunks quad*8..; DS in-order per wave
            x0 = scr4[c16 * 16 + quad * 2];
            x1 = scr4[c16 * 16 + quad * 2 + 1];
            x2 = scr4[c16 * 16 + 8 + quad * 2];
            x3 = scr4[c16 * 16 + 9 + quad * 2];
        }
        Frag pa0, pa1;
        pa0.u[0] = pk(x0.x, x0.y); pa0.u[1] = pk(x0.z, x0.w);
        pa0.u[2] = pk(x1.x, x1.y); pa0.u[3] = pk(x1.z, x1.w);
        pa1.u[0] = pk(x2.x, x2.y); pa1.u[1] = pk(x2.z, x2.w);
        pa1.u[2] = pk(x3.x, x3.y); pa1.u[3] = pk(x3.z, x3.w);
        #pragma unroll
        for (int nt = 0; nt < 4; ++nt) {
            Frag b0, b1;
            b0.v = fr[1536 + (nt * 2 + 0) * 64 + lane];
            b1.v = fr[1536 + (nt * 2 + 1) * 64 + lane];
            f32x4 acc = {gbr[nt], gbr[nt], gbr[nt], gbr[nt]};
            acc = MFMA(pa0.s, b0.s, acc);
            acc = MFMA(pa1.s, b1.s, acc);
            if (quad < 2) {
                #pragma unroll
                for (int r = 0; r < 4; ++r)
                    phig_s[(quad * 4 + r) * 65 + nt * 16 + c16] = acc[r];
            }
        }
    }

    // commit point 0 to LDS slot 0; reg-stage point 1; prefetch nxyz for point 1
    {
        float4* s0 = (float4*)nfl;
        #pragma unroll
        for (int j = 0; j < 4; ++j) s0[j * 64 + lane] = x[j];
    }
    #pragma unroll
    for (int j = 0; j < 4; ++j)
        x[j] = *(const float4*)(nfbase + 4096 + soff[j]);
    float nvn = (lane < 48) ? nxyz[(size_t)g0 * 48 + 48 + lane] : 0.f;

    #pragma unroll 1
    for (int i = 0; i < GPW; ++i) {
        const int n = g0 + i;

        // commit point i+1 (in regs) to the other slot; reg-stage point i+2
        if (i + 1 < GPW) {
            float4* sw = (float4*)(nfl + ((i + 1) & 1) * 1024);
            #pragma unroll
            for (int j = 0; j < 4; ++j) sw[j * 64 + lane] = x[j];
            if (i + 2 < GPW) {
                #pragma unroll
                for (int j = 0; j < 4; ++j)
                    x[j] = *(const float4*)(nfbase + (size_t)(i + 2) * 4096 + soff[j]);
            }
        }

        const float* nfp = nfl + (i & 1) * 1024;

        // nf A-frags from LDS (inverse rotation; 2-way banks = free)
        int b0 = c16 * 64 + (((quad * 2     + c16) & 15) << 2);
        int b1 = c16 * 64 + (((quad * 2 + 1 + c16) & 15) << 2);
        int b2 = c16 * 64 + (((quad * 2 + 8 + c16) & 15) << 2);
        int b3 = c16 * 64 + (((quad * 2 + 9 + c16) & 15) << 2);
        float4 x0 = *(const float4*)(nfp + b0);
        float4 x1 = *(const float4*)(nfp + b1);
        float4 x2 = *(const float4*)(nfp + b2);
        float4 x3 = *(const float4*)(nfp + b3);
        Frag na0, na1;
        na0.u[0] = pk(x0.x, x0.y); na0.u[1] = pk(x0.z, x0.w);
        na0.u[2] = pk(x1.x, x1.y); na0.u[3] = pk(x1.z, x1.w);
        na1.u[0] = pk(x2.x, x2.y); na1.u[1] = pk(x2.z, x2.w);
        na1.u[2] = pk(x3.x, x3.y); na1.u[3] = pk(x3.z, x3.w);

        // phig values for this point
        float ph[4];
        #pragma unroll
        for (int nt = 0; nt < 4; ++nt) ph[nt] = phig_s[i * 65 + nt * 16 + c16];
        // this point's dxyz rows
        float4 dd[4];
        #pragma unroll
        for (int r = 0; r < 4; ++r)
            dd[r] = ((const float4*)dxyz)[(i & 1) * 16 + quad * 4 + r];

        // write next point's dxyz (uses prefetched nvn), then prefetch nxyz i+2
        if (i + 1 < GPW) {
            if (lane < 48)
                dxyz[((i + 1) & 1) * 64 + k3 * 4 + c3] = pxyz_s[(i + 1) * 3 + c3] - nvn;
            if (i + 2 < GPW)
                nvn = (lane < 48) ? nxyz[((size_t)n + 2) * 48 + lane] : 0.f;
        }

        // u = diff@Wc + bc, relu -> delta in C-layout; pack transpose into utr
        float d_c[4][4];
        #pragma unroll
        for (int nt = 0; nt < 4; ++nt) {
            #pragma unroll
            for (int r = 0; r < 4; ++r) {
                float u = fmaf(dd[r].x, wc[nt].x,
                          fmaf(dd[r].y, wc[nt].y,
                          fmaf(dd[r].z, wc[nt].z, wc[nt].w)));
                d_c[nt][r] = fmaxf(u, 0.f);
            }
        }
        #pragma unroll
        for (int r = 0; r < 4; ++r) {
            int row = (quad * 4 + r) * 34;
            utr[row + c16]      = pk(d_c[0][r], d_c[1][r]);
            utr[row + 16 + c16] = pk(d_c[2][r], d_c[3][r]);
        }

        // alpha = nf@Wa + ba (delta added after); overlaps utr write latency
        f32x4 aacc[4];
        #pragma unroll
        for (int nt = 0; nt < 4; ++nt) {
            aacc[nt] = f32x4{ba_r[nt], ba_r[nt], ba_r[nt], ba_r[nt]};
            aacc[nt] = MFMA(na0.s, wa[nt * 2 + 0].s, aacc[nt]);
            aacc[nt] = MFMA(na1.s, wa[nt * 2 + 1].s, aacc[nt]);
        }
        // gamma = phig - nf@WpsiG ...
        f32x4 gacc[4];
        #pragma unroll
        for (int nt = 0; nt < 4; ++nt) {
            gacc[nt] = f32x4{ph[nt], ph[nt], ph[nt], ph[nt]};
            gacc[nt] = MFMA(na0.s, wpsig[nt * 2 + 0].s, gacc[nt]);
            gacc[nt] = MFMA(na1.s, wpsig[nt * 2 + 1].s, gacc[nt]);
        }
        // ... + delta@Wg (read back transposed delta as ready-made A-frags)
        Frag da0, da1;
        {
            const uint_t* rowp = utr + c16 * 34 + quad * 4;
            uint2 a = *(const uint2*)(rowp);
            uint2 b = *(const uint2*)(rowp + 2);
            uint2 c = *(const uint2*)(rowp + 16);
            uint2 d = *(const uint2*)(rowp + 18);
            da0.u[0] = a.x; da0.u[1] = a.y; da0.u[2] = b.x; da0.u[3] = b.y;
            da1.u[0] = c.x; da1.u[1] = c.y; da1.u[2] = d.x; da1.u[3] = d.y;
        }
        #pragma unroll
        for (int nt = 0; nt < 4; ++nt) {
            gacc[nt] = MFMA(da0.s, wg[nt * 2 + 0].s, gacc[nt]);
            gacc[nt] = MFMA(da1.s, wg[nt * 2 + 1].s, gacc[nt]);
        }
        // alpha finalize
        #pragma unroll
        for (int nt = 0; nt < 4; ++nt)
            #pragma unroll
            for (int r = 0; r < 4; ++r) aacc[nt][r] += d_c[nt][r];

        // softmax over features (no max-sub: |gamma| small by construction)
        float e[4][4], smi[4];
        #pragma unroll
        for (int r = 0; r < 4; ++r) {
            float s = 0.f;
            #pragma unroll
            for (int nt = 0; nt < 4; ++nt) { e[nt][r] = __expf(gacc[nt][r]); s += e[nt][r]; }
            #pragma unroll
            for (int d2 = 1; d2 < 16; d2 <<= 1) s += __shfl_xor(s, d2);
            smi[r] = __builtin_amdgcn_rcpf(s);
        }
        // out_d = sum_k rho*alpha
        float p0 = 0.f, p1 = 0.f, p2 = 0.f, p3 = 0.f;
        #pragma unroll
        for (int r = 0; r < 4; ++r) {
            p0 = fmaf(e[0][r] * smi[r], aacc[0][r], p0);
            p1 = fmaf(e[1][r] * smi[r], aacc[1][r], p1);
            p2 = fmaf(e[2][r] * smi[r], aacc[2][r], p2);
            p3 = fmaf(e[3][r] * smi[r], aacc[3][r], p3);
        }
        p0 += __shfl_xor(p0, 16); p0 += __shfl_xor(p0, 32);
        p1 += __shfl_xor(p1, 16); p1 += __shfl_xor(p1, 32);
        p2 += __shfl_xor(p2, 16); p2 += __shfl_xor(p2, 32);
        p3 += __shfl_xor(p3, 16); p3 += __shfl_xor(p3, 32);
        float sel = (quad == 0) ? p0 : (quad == 1) ? p1 : (quad == 2) ? p2 : p3;
        obuf[i * 64 + lane] = sel;                 // buffer; wide store after loop

    }

    // one contiguous 2 KB store per wave, 32B per lane (true-size write counting)
    float4 o0 = ((const float4*)obuf)[lane * 2];
    float4 o1 = ((const float4*)obuf)[lane * 2 + 1];
    float4* og = (float4*)(out + (size_t)g0 * 64);
    og[lane * 2]     = o0;
    og[lane * 2 + 1] = o1;
}

extern "C" void kernel_launch(void* const* d_in, const int* in_sizes, int n_in,
                              void* d_out, int out_size, void* d_ws, size_t ws_size,
                              hipStream_t stream) {
    const float* pxyz  = (const float*)d_in[0];
    const float* pfeat = (const float*)d_in[1];
    const float* nxyz  = (const float*)d_in[2];
    const float* nfeat = (const float*)d_in[3];
    const float* Wphi  = (const float*)d_in[4];
    const float* bphi  = (const float*)d_in[5];
    const float* Wpsi  = (const float*)d_in[6];
    const float* bpsi  = (const float*)d_in[7];
    const float* Wa    = (const float*)d_in[8];
    const float* ba    = (const float*)d_in[9];
    const float* Wg    = (const float*)d_in[10];
    const float* bg    = (const float*)d_in[11];
    const float* Wd1   = (const float*)d_in[12];
    const float* bd1   = (const float*)d_in[13];
    const float* Wd2   = (const float*)d_in[14];
    const float* bd2   = (const float*)d_in[15];
    float* ws = (float*)d_ws;

    pt_prep<<<33, 256, 0, stream>>>(Wphi, bphi, Wpsi, bpsi, Wa, ba, Wg, bg,
                                    Wd1, bd1, Wd2, bd2, ws);
    pt_main<<<NBLOCKS, 256, 0, stream>>>(pxyz, pfeat, nxyz, nfeat, ws, (float*)d_out);
}

// Round 5
// 375.830 us; speedup vs baseline: 1.0054x; 1.0054x over previous
//
#include <hip/hip_runtime.h>
#include <hip/hip_bf16.h>

typedef unsigned int uint_t;
typedef __attribute__((ext_vector_type(8))) short bf16x8;   // MFMA A/B frag (4 VGPRs)
typedef __attribute__((ext_vector_type(4))) float f32x4;    // MFMA C/D frag

#define NPTS 50000
#define DIM  64
#define KNB  16
#define GPW  8                  // points per wave (one group per wave)
#define NGROUPS (NPTS / GPW)    // 6250
#define WPB  4                  // waves per block
#define NBLOCKS ((NGROUPS + WPB - 1) / WPB)

// ws layout in 32-bit words: frag images are [f*256 + lane*4 + w]
#define FR_WA    0       // Wa frag image (8 frags)
#define FR_PSIG  2048    // -(Wpsi@Wg) frag image
#define FR_WG    4096    // Wg, rows sigma-permuted, frag image
#define FR_PHIG  6144    // (Wphi@Wg) frag image
#define WC4      8192    // 64 x float4 (wcx,wcy,wcz,wbc)
#define GB       8448    // (bphi-bpsi)@Wg + bg
#define BA       8512    // b_alpha

__device__ __forceinline__ uint_t pk(float a, float b) {
    union { __hip_bfloat162 h; uint_t u; } cv;
    cv.h = __float22bfloat162_rn(float2{a, b});
    return cv.u;
}

union Frag { uint_t u[4]; bf16x8 s; uint4 v; };

// sigma: row-permutation of Wg so that the utr writer's in-lane (nt0,nt1)/(nt2,nt3)
// pairs land as the reader's consecutive A-frag k-dim pairs.
__device__ __forceinline__ int sigma(int k) {
    int t = k >> 1;
    return (t & 15) + 32 * (t >> 4) + 16 * (k & 1);
}

__global__ void pt_prep(const float* __restrict__ Wphi, const float* __restrict__ bphi,
                        const float* __restrict__ Wpsi, const float* __restrict__ bpsi,
                        const float* __restrict__ Wa,   const float* __restrict__ ba,
                        const float* __restrict__ Wg,   const float* __restrict__ bg,
                        const float* __restrict__ Wd1,  const float* __restrict__ bd1,
                        const float* __restrict__ Wd2,  const float* __restrict__ bd2,
                        float* __restrict__ ws) {
    int b = blockIdx.x, t = threadIdx.x;
    uint_t* wsu = (uint_t*)ws;
    if (b < 32) {
        int gid  = b * 256 + t;             // [0, 8192)
        int img  = gid >> 11;               // 0..3
        int rem  = gid & 2047;
        int f    = rem >> 8;                // 0..7  (nt = f>>1, s = f&1)
        int lane = (rem >> 2) & 63;
        int w    = rem & 3;
        int k0   = (f & 1) * 32 + (lane >> 4) * 8 + 2 * w;
        int k1   = k0 + 1;
        int n    = (f >> 1) * 16 + (lane & 15);
        float v0, v1;
        if (img == 0) {                     // Wa
            v0 = Wa[k0 * 64 + n]; v1 = Wa[k1 * 64 + n];
            wsu[FR_WA + rem] = pk(v0, v1);
        } else if (img == 1) {              // -(Wpsi@Wg)
            float a0 = 0.f, a1 = 0.f;
            for (int c = 0; c < 64; ++c) {
                float wgc = Wg[c * 64 + n];
                a0 += Wpsi[k0 * 64 + c] * wgc;
                a1 += Wpsi[k1 * 64 + c] * wgc;
            }
            wsu[FR_PSIG + rem] = pk(-a0, -a1);
        } else if (img == 2) {              // Wg sigma-row-permuted
            v0 = Wg[sigma(k0) * 64 + n]; v1 = Wg[sigma(k1) * 64 + n];
            wsu[FR_WG + rem] = pk(v0, v1);
        } else {                            // Wphi@Wg
            float a0 = 0.f, a1 = 0.f;
            for (int c = 0; c < 64; ++c) {
                float wgc = Wg[c * 64 + n];
                a0 += Wphi[k0 * 64 + c] * wgc;
                a1 += Wphi[k1 * 64 + c] * wgc;
            }
            wsu[FR_PHIG + rem] = pk(a0, a1);
        }
    } else if (t < 64) {
        // wc4: folded W_d1@W_d2 (+ folded bias), gb, ba
        float wx = 0.f, wy = 0.f, wz = 0.f;
        for (int m = 0; m < 64; ++m) {
            float w2 = Wd2[m * 64 + t];
            wx += Wd1[m] * w2;
            wy += Wd1[64 + m] * w2;
            wz += Wd1[128 + m] * w2;
        }
        float wb = bd2[t];
        for (int m = 0; m < 64; ++m) wb += bd1[m] * Wd2[m * 64 + t];
        ws[WC4 + t * 4 + 0] = wx;
        ws[WC4 + t * 4 + 1] = wy;
        ws[WC4 + t * 4 + 2] = wz;
        ws[WC4 + t * 4 + 3] = wb;
        float g = bg[t];
        for (int c = 0; c < 64; ++c) g += (bphi[c] - bpsi[c]) * Wg[c * 64 + t];
        ws[GB + t] = g;
        ws[BA + t] = ba[t];
    }
}

#define MFMA(A, B, C) __builtin_amdgcn_mfma_f32_16x16x32_bf16((A), (B), (C), 0, 0, 0)

// per-wave LDS word layout:
// phig 520 | utr 544 (also pfeat bounce scratch in preamble) | dxyz 128 | pxyz 32
// | obuf 512 | nf 2 slots x 1024 (double-buffered point features)
#define O_PHIG 0
#define O_UTR  520
#define O_DXY  1064
#define O_PXY  1192
#define O_OBUF 1224
#define O_NF   1736
#define WAREA  (O_NF + 2 * 1024)   // 3784 words = 15136 B/wave

// pin a Frag's 4 dwords as asm-defined values (prevents rematerialization of
// the originating loads; per-scalar "+v" — clang rejects tied 128-bit operands)
#define PIN_FRAG(F) asm volatile("" : "+v"((F).u[0]), "+v"((F).u[1]), \
                                      "+v"((F).u[2]), "+v"((F).u[3]))

__global__ __launch_bounds__(256, 2)
void pt_main(const float* __restrict__ pxyz, const float* __restrict__ pfeat,
             const float* __restrict__ nxyz, const float* __restrict__ nfeat,
             const float* __restrict__ ws,   float* __restrict__ out) {
    __shared__ float lds[WPB][WAREA];

    const int t    = threadIdx.x;
    const int wv   = t >> 6;
    const int lane = t & 63;
    const int c16  = lane & 15;
    const int quad = lane >> 4;

    const int g = blockIdx.x * WPB + wv;
    if (g >= NGROUPS) return;            // no block-level barriers anywhere

    float*  W      = lds[wv];
    float*  phig_s = W + O_PHIG;
    uint_t* utr    = (uint_t*)(W + O_UTR);
    float*  dxyz   = W + O_DXY;
    float*  pxyz_s = W + O_PXY;
    float*  obuf   = W + O_OBUF;
    float*  nfl    = W + O_NF;

    const int g0 = g * GPW;
    const int k3 = lane / 3, c3 = lane - k3 * 3;   // lane<48: (neighbor, component)

    // per-lane rotated source offsets: instruction j's 64 lanes densely cover
    // bytes [j*1024,(j+1)*1024) of the point's 4KB row-block (every 32B sector
    // fully covered WITHIN one instruction -> no sector over-fetch).
    int soff[4];
    #pragma unroll
    for (int j = 0; j < 4; ++j) {
        int row = j * 4 + quad;                       // neighbor row this lane covers
        soff[j] = row * 256 + (((c16 - row) & 15) << 4);
    }

    const char* nfbase = (const char*)nfeat + (size_t)g0 * 4096;

    // reg-stage point 0 (dense loads), issued first so latency hides under preamble
    float4 x[4];
    #pragma unroll
    for (int j = 0; j < 4; ++j)
        x[j] = *(const float4*)(nfbase + soff[j]);

    // ---- persistent weights in registers (zero-latency MFMA operands) ----
    const uint4* fr = (const uint4*)ws;       // frag uint4 index = IMG/4 + f*64 + lane
    Frag wa[8], wpsig[8], wg[8];
    #pragma unroll
    for (int f = 0; f < 8; ++f) {
        wa[f].v    = fr[        f * 64 + lane];
        wpsig[f].v = fr[ 512 +  f * 64 + lane];
        wg[f].v    = fr[1024 +  f * 64 + lane];
    }
    // PIN: asm-define the weight frags so the allocator cannot rematerialize
    // the global loads inside the loop (R3: VGPR_Count=116 proved it re-fetched
    // all 24 frags from L2 every iteration -> latency-bound at 137us).
    #pragma unroll
    for (int f = 0; f < 8; ++f) {
        PIN_FRAG(wa[f]);
        PIN_FRAG(wpsig[f]);
        PIN_FRAG(wg[f]);
    }
    float4 wc[4];
    float ba_r[4], gbr[4];
    #pragma unroll
    for (int nt = 0; nt < 4; ++nt) {
        int d = nt * 16 + c16;
        wc[nt]   = ((const float4*)(ws + WC4))[d];
        ba_r[nt] = ws[BA + d];
        gbr[nt]  = ws[GB + d];
    }
    #pragma unroll
    for (int nt = 0; nt < 4; ++nt) {
        asm volatile("" : "+v"(wc[nt].x), "+v"(wc[nt].y),
                          "+v"(wc[nt].z), "+v"(wc[nt].w));
        asm volatile("" : "+v"(ba_r[nt]), "+v"(gbr[nt]));
    }

    if (lane < 24) pxyz_s[lane] = pxyz[g0 * 3 + lane];
    float nv0 = (lane < 48) ? nxyz[(size_t)g0 * 48 + lane] : 0.f;
    if (lane < 48) dxyz[k3 * 4 + c3] = pxyz_s[c3] - nv0;   // point 0, buf 0

    // pfeat: dense load -> LDS bounce (utr region as scratch), then frag reads.
    {
        float4* scr4 = (float4*)(W + O_UTR);
        const float4* pfg4 = (const float4*)(pfeat + (size_t)g0 * 64);
        if (lane < 32) {
            #pragma unroll
            for (int j = 0; j < 4; ++j)
                scr4[j * 32 + lane] = pfg4[j * 32 + lane];
        }
        float4 x0{}, x1{}, x2{}, x3{};
        if (c16 < 8) {                      // row c16, chunks quad*8..; DS in-order per wave
            x0 = scr4[c16 * 16 + quad * 2];
            x1 = scr4[c16 * 16 + quad * 2 + 1];
            x2 = scr4[c16 * 16 + 8 + quad * 2];
            x3 = scr4[c16 * 16 + 9 + quad * 2];
        }
        Frag pa0, pa1;
        pa0.u[0] = pk(x0.x, x0.y); pa0.u[1] = pk(x0.z, x0.w);
        pa0.u[2] = pk(x1.x, x1.y); pa0.u[3] = pk(x1.z, x1.w);
        pa1.u[0] = pk(x2.x, x2.y); pa1.u[1] = pk(x2.z, x2.w);
        pa1.u[2] = pk(x3.x, x3.y); pa1.u[3] = pk(x3.z, x3.w);
        #pragma unroll
        for (int nt = 0; nt < 4; ++nt) {
            Frag b0, b1;
            b0.v = fr[1536 + (nt * 2 + 0) * 64 + lane];
            b1.v = fr[1536 + (nt * 2 + 1) * 64 + lane];
            f32x4 acc = {gbr[nt], gbr[nt], gbr[nt], gbr[nt]};
            acc = MFMA(pa0.s, b0.s, acc);
            acc = MFMA(pa1.s, b1.s, acc);
            if (quad < 2) {
                #pragma unroll
                for (int r = 0; r < 4; ++r)
                    phig_s[(quad * 4 + r) * 65 + nt * 16 + c16] = acc[r];
            }
        }
    }

    // commit point 0 to LDS slot 0; reg-stage point 1; prefetch nxyz for point 1
    {
        float4* s0 = (float4*)nfl;
        #pragma unroll
        for (int j = 0; j < 4; ++j) s0[j * 64 + lane] = x[j];
    }
    #pragma unroll
    for (int j = 0; j < 4; ++j)
        x[j] = *(const float4*)(nfbase + 4096 + soff[j]);
    float nvn = (lane < 48) ? nxyz[(size_t)g0 * 48 + 48 + lane] : 0.f;

    #pragma unroll 1
    for (int i = 0; i < GPW; ++i) {
        const int n = g0 + i;

        // commit point i+1 (in regs) to the other slot; reg-stage point i+2
        if (i + 1 < GPW) {
            float4* sw = (float4*)(nfl + ((i + 1) & 1) * 1024);
            #pragma unroll
            for (int j = 0; j < 4; ++j) sw[j * 64 + lane] = x[j];
            if (i + 2 < GPW) {
                #pragma unroll
                for (int j = 0; j < 4; ++j)
                    x[j] = *(const float4*)(nfbase + (size_t)(i + 2) * 4096 + soff[j]);
            }
        }

        const float* nfp = nfl + (i & 1) * 1024;

        // nf A-frags from LDS (inverse rotation; 2-way banks = free)
        int b0 = c16 * 64 + (((quad * 2     + c16) & 15) << 2);
        int b1 = c16 * 64 + (((quad * 2 + 1 + c16) & 15) << 2);
        int b2 = c16 * 64 + (((quad * 2 + 8 + c16) & 15) << 2);
        int b3 = c16 * 64 + (((quad * 2 + 9 + c16) & 15) << 2);
        float4 x0 = *(const float4*)(nfp + b0);
        float4 x1 = *(const float4*)(nfp + b1);
        float4 x2 = *(const float4*)(nfp + b2);
        float4 x3 = *(const float4*)(nfp + b3);
        Frag na0, na1;
        na0.u[0] = pk(x0.x, x0.y); na0.u[1] = pk(x0.z, x0.w);
        na0.u[2] = pk(x1.x, x1.y); na0.u[3] = pk(x1.z, x1.w);
        na1.u[0] = pk(x2.x, x2.y); na1.u[1] = pk(x2.z, x2.w);
        na1.u[2] = pk(x3.x, x3.y); na1.u[3] = pk(x3.z, x3.w);

        // phig values for this point
        float ph[4];
        #pragma unroll
        for (int nt = 0; nt < 4; ++nt) ph[nt] = phig_s[i * 65 + nt * 16 + c16];
        // this point's dxyz rows
        float4 dd[4];
        #pragma unroll
        for (int r = 0; r < 4; ++r)
            dd[r] = ((const float4*)dxyz)[(i & 1) * 16 + quad * 4 + r];

        // write next point's dxyz (uses prefetched nvn), then prefetch nxyz i+2
        if (i + 1 < GPW) {
            if (lane < 48)
                dxyz[((i + 1) & 1) * 64 + k3 * 4 + c3] = pxyz_s[(i + 1) * 3 + c3] - nvn;
            if (i + 2 < GPW)
                nvn = (lane < 48) ? nxyz[((size_t)n + 2) * 48 + lane] : 0.f;
        }

        // u = diff@Wc + bc, relu -> delta in C-layout; pack transpose into utr
        float d_c[4][4];
        #pragma unroll
        for (int nt = 0; nt < 4; ++nt) {
            #pragma unroll
            for (int r = 0; r < 4; ++r) {
                float u = fmaf(dd[r].x, wc[nt].x,
                          fmaf(dd[r].y, wc[nt].y,
                          fmaf(dd[r].z, wc[nt].z, wc[nt].w)));
                d_c[nt][r] = fmaxf(u, 0.f);
            }
        }
        #pragma unroll
        for (int r = 0; r < 4; ++r) {
            int row = (quad * 4 + r) * 34;
            utr[row + c16]      = pk(d_c[0][r], d_c[1][r]);
            utr[row + 16 + c16] = pk(d_c[2][r], d_c[3][r]);
        }

        // alpha = nf@Wa + (ba + delta): fold d_c into the init so it dies here
        // (cuts ~16 live VGPRs across the gamma-MFMA region).
        f32x4 aacc[4];
        #pragma unroll
        for (int nt = 0; nt < 4; ++nt) {
            aacc[nt] = f32x4{ba_r[nt] + d_c[nt][0], ba_r[nt] + d_c[nt][1],
                             ba_r[nt] + d_c[nt][2], ba_r[nt] + d_c[nt][3]};
            aacc[nt] = MFMA(na0.s, wa[nt * 2 + 0].s, aacc[nt]);
            aacc[nt] = MFMA(na1.s, wa[nt * 2 + 1].s, aacc[nt]);
        }
        // gamma = phig - nf@WpsiG ...
        f32x4 gacc[4];
        #pragma unroll
        for (int nt = 0; nt < 4; ++nt) {
            gacc[nt] = f32x4{ph[nt], ph[nt], ph[nt], ph[nt]};
            gacc[nt] = MFMA(na0.s, wpsig[nt * 2 + 0].s, gacc[nt]);
            gacc[nt] = MFMA(na1.s, wpsig[nt * 2 + 1].s, gacc[nt]);
        }
        // ... + delta@Wg (read back transposed delta as ready-made A-frags)
        Frag da0, da1;
        {
            const uint_t* rowp = utr + c16 * 34 + quad * 4;
            uint2 a = *(const uint2*)(rowp);
            uint2 b = *(const uint2*)(rowp + 2);
            uint2 c = *(const uint2*)(rowp + 16);
            uint2 d = *(const uint2*)(rowp + 18);
            da0.u[0] = a.x; da0.u[1] = a.y; da0.u[2] = b.x; da0.u[3] = b.y;
            da1.u[0] = c.x; da1.u[1] = c.y; da1.u[2] = d.x; da1.u[3] = d.y;
        }
        #pragma unroll
        for (int nt = 0; nt < 4; ++nt) {
            gacc[nt] = MFMA(da0.s, wg[nt * 2 + 0].s, gacc[nt]);
            gacc[nt] = MFMA(da1.s, wg[nt * 2 + 1].s, gacc[nt]);
        }

        // softmax over features (no max-sub: |gamma| small by construction)
        float e[4][4], smi[4];
        #pragma unroll
        for (int r = 0; r < 4; ++r) {
            float s = 0.f;
            #pragma unroll
            for (int nt = 0; nt < 4; ++nt) { e[nt][r] = __expf(gacc[nt][r]); s += e[nt][r]; }
            #pragma unroll
            for (int d2 = 1; d2 < 16; d2 <<= 1) s += __shfl_xor(s, d2);
            smi[r] = __builtin_amdgcn_rcpf(s);
        }
        // out_d = sum_k rho*alpha
        float p0 = 0.f, p1 = 0.f, p2 = 0.f, p3 = 0.f;
        #pragma unroll
        for (int r = 0; r < 4; ++r) {
            p0 = fmaf(e[0][r] * smi[r], aacc[0][r], p0);
            p1 = fmaf(e[1][r] * smi[r], aacc[1][r], p1);
            p2 = fmaf(e[2][r] * smi[r], aacc[2][r], p2);
            p3 = fmaf(e[3][r] * smi[r], aacc[3][r], p3);
        }
        p0 += __shfl_xor(p0, 16); p0 += __shfl_xor(p0, 32);
        p1 += __shfl_xor(p1, 16); p1 += __shfl_xor(p1, 32);
        p2 += __shfl_xor(p2, 16); p2 += __shfl_xor(p2, 32);
        p3 += __shfl_xor(p3, 16); p3 += __shfl_xor(p3, 32);
        float sel = (quad == 0) ? p0 : (quad == 1) ? p1 : (quad == 2) ? p2 : p3;
        obuf[i * 64 + lane] = sel;                 // buffer; wide store after loop

    }

    // one contiguous 2 KB store per wave, 32B per lane (true-size write counting)
    float4 o0 = ((const float4*)obuf)[lane * 2];
    float4 o1 = ((const float4*)obuf)[lane * 2 + 1];
    float4* og = (float4*)(out + (size_t)g0 * 64);
    og[lane * 2]     = o0;
    og[lane * 2 + 1] = o1;
}

extern "C" void kernel_launch(void* const* d_in, const int* in_sizes, int n_in,
                              void* d_out, int out_size, void* d_ws, size_t ws_size,
                              hipStream_t stream) {
    const float* pxyz  = (const float*)d_in[0];
    const float* pfeat = (const float*)d_in[1];
    const float* nxyz  = (const float*)d_in[2];
    const float* nfeat = (const float*)d_in[3];
    const float* Wphi  = (const float*)d_in[4];
    const float* bphi  = (const float*)d_in[5];
    const float* Wpsi  = (const float*)d_in[6];
    const float* bpsi  = (const float*)d_in[7];
    const float* Wa    = (const float*)d_in[8];
    const float* ba    = (const float*)d_in[9];
    const float* Wg    = (const float*)d_in[10];
    const float* bg    = (const float*)d_in[11];
    const float* Wd1   = (const float*)d_in[12];
    const float* bd1   = (const float*)d_in[13];
    const float* Wd2   = (const float*)d_in[14];
    const float* bd2   = (const float*)d_in[15];
    float* ws = (float*)d_ws;

    pt_prep<<<33, 256, 0, stream>>>(Wphi, bphi, Wpsi, bpsi, Wa, ba, Wg, bg,
                                    Wd1, bd1, Wd2, bd2, ws);
    pt_main<<<NBLOCKS, 256, 0, stream>>>(pxyz, pfeat, nxyz, nfeat, ws, (float*)d_out);
}

// Round 6
// 353.983 us; speedup vs baseline: 1.0675x; 1.0617x over previous
//
#include <hip/hip_runtime.h>
#include <hip/hip_bf16.h>

typedef unsigned int uint_t;
typedef __attribute__((ext_vector_type(8))) short bf16x8;   // MFMA A/B frag (4 VGPRs)
typedef __attribute__((ext_vector_type(4))) float f32x4;    // MFMA C/D frag

#define NPTS 50000
#define DIM  64
#define KNB  16
#define GPW  8                  // points per wave (one group per wave)
#define NGROUPS (NPTS / GPW)    // 6250
#define WPB  4                  // waves per block
#define NBLOCKS ((NGROUPS + WPB - 1) / WPB)

// ws layout in 32-bit words: frag images are [f*256 + lane*4 + w]
#define FR_WA    0       // Wa frag image (8 frags)
#define FR_PSIG  2048    // -(Wpsi@Wg) frag image
#define FR_WG    4096    // Wg, rows sigma-permuted, frag image
#define FR_PHIG  6144    // (Wphi@Wg) frag image
#define WC4      8192    // 64 x float4 (wcx,wcy,wcz,wbc)
#define GB       8448    // (bphi-bpsi)@Wg + bg
#define BA       8512    // b_alpha

__device__ __forceinline__ uint_t pk(float a, float b) {
    union { __hip_bfloat162 h; uint_t u; } cv;
    cv.h = __float22bfloat162_rn(float2{a, b});
    return cv.u;
}

union Frag { uint_t u[4]; bf16x8 s; uint4 v; };

// sigma: row-permutation of Wg so that the utr writer's in-lane (nt0,nt1)/(nt2,nt3)
// pairs land as the reader's consecutive A-frag k-dim pairs.
__device__ __forceinline__ int sigma(int k) {
    int t = k >> 1;
    return (t & 15) + 32 * (t >> 4) + 16 * (k & 1);
}

__global__ void pt_prep(const float* __restrict__ Wphi, const float* __restrict__ bphi,
                        const float* __restrict__ Wpsi, const float* __restrict__ bpsi,
                        const float* __restrict__ Wa,   const float* __restrict__ ba,
                        const float* __restrict__ Wg,   const float* __restrict__ bg,
                        const float* __restrict__ Wd1,  const float* __restrict__ bd1,
                        const float* __restrict__ Wd2,  const float* __restrict__ bd2,
                        float* __restrict__ ws) {
    int b = blockIdx.x, t = threadIdx.x;
    uint_t* wsu = (uint_t*)ws;
    if (b < 32) {
        int gid  = b * 256 + t;             // [0, 8192)
        int img  = gid >> 11;               // 0..3
        int rem  = gid & 2047;
        int f    = rem >> 8;                // 0..7  (nt = f>>1, s = f&1)
        int lane = (rem >> 2) & 63;
        int w    = rem & 3;
        int k0   = (f & 1) * 32 + (lane >> 4) * 8 + 2 * w;
        int k1   = k0 + 1;
        int n    = (f >> 1) * 16 + (lane & 15);
        float v0, v1;
        if (img == 0) {                     // Wa
            v0 = Wa[k0 * 64 + n]; v1 = Wa[k1 * 64 + n];
            wsu[FR_WA + rem] = pk(v0, v1);
        } else if (img == 1) {              // -(Wpsi@Wg)
            float a0 = 0.f, a1 = 0.f;
            for (int c = 0; c < 64; ++c) {
                float wgc = Wg[c * 64 + n];
                a0 += Wpsi[k0 * 64 + c] * wgc;
                a1 += Wpsi[k1 * 64 + c] * wgc;
            }
            wsu[FR_PSIG + rem] = pk(-a0, -a1);
        } else if (img == 2) {              // Wg sigma-row-permuted
            v0 = Wg[sigma(k0) * 64 + n]; v1 = Wg[sigma(k1) * 64 + n];
            wsu[FR_WG + rem] = pk(v0, v1);
        } else {                            // Wphi@Wg
            float a0 = 0.f, a1 = 0.f;
            for (int c = 0; c < 64; ++c) {
                float wgc = Wg[c * 64 + n];
                a0 += Wphi[k0 * 64 + c] * wgc;
                a1 += Wphi[k1 * 64 + c] * wgc;
            }
            wsu[FR_PHIG + rem] = pk(a0, a1);
        }
    } else if (t < 64) {
        // wc4: folded W_d1@W_d2 (+ folded bias), gb, ba
        float wx = 0.f, wy = 0.f, wz = 0.f;
        for (int m = 0; m < 64; ++m) {
            float w2 = Wd2[m * 64 + t];
            wx += Wd1[m] * w2;
            wy += Wd1[64 + m] * w2;
            wz += Wd1[128 + m] * w2;
        }
        float wb = bd2[t];
        for (int m = 0; m < 64; ++m) wb += bd1[m] * Wd2[m * 64 + t];
        ws[WC4 + t * 4 + 0] = wx;
        ws[WC4 + t * 4 + 1] = wy;
        ws[WC4 + t * 4 + 2] = wz;
        ws[WC4 + t * 4 + 3] = wb;
        float g = bg[t];
        for (int c = 0; c < 64; ++c) g += (bphi[c] - bpsi[c]) * Wg[c * 64 + t];
        ws[GB + t] = g;
        ws[BA + t] = ba[t];
    }
}

#define MFMA(A, B, C) __builtin_amdgcn_mfma_f32_16x16x32_bf16((A), (B), (C), 0, 0, 0)

// per-wave LDS (words): phig 8*65=520 | utr 16*34=544 | dxyz 2*16*4=128 | pxyz 32 | obuf 512
#define WAREA 1736

__device__ __forceinline__ uint_t bperm(int byteaddr, uint_t v) {
    return (uint_t)__builtin_amdgcn_ds_bpermute(byteaddr, (int)v);
}

__global__ __launch_bounds__(256, 2)
void pt_main(const float* __restrict__ pxyz, const float* __restrict__ pfeat,
             const float* __restrict__ nxyz, const float* __restrict__ nfeat,
             const float* __restrict__ ws,   float* __restrict__ out) {
    __shared__ float lds[WPB][WAREA];

    const int t    = threadIdx.x;
    const int wv   = t >> 6;
    const int lane = t & 63;
    const int c16  = lane & 15;
    const int quad = lane >> 4;

    const int g = blockIdx.x * WPB + wv;
    if (g >= NGROUPS) return;

    float*  phig_s = &lds[wv][0];
    uint_t* utr    = (uint_t*)(phig_s + 520);
    float*  dxyz   = (float*)(utr + 544);
    float*  pxyz_s = dxyz + 128;
    float*  obuf   = pxyz_s + 32;

    // ---- persistent weights ----
    const uint4* fr = (const uint4*)ws;       // frag uint4 index = IMG/4 + f*64 + lane
    Frag wa[8], wpsig[8], wg[8];
    #pragma unroll
    for (int f = 0; f < 8; ++f) {
        wa[f].v    = fr[           f * 64 + lane];
        wpsig[f].v = fr[ 512 +     f * 64 + lane];
        wg[f].v    = fr[1024 +     f * 64 + lane];
    }
    float4 wc[4];
    float ba_r[4], gbr[4];
    #pragma unroll
    for (int nt = 0; nt < 4; ++nt) {
        int d = nt * 16 + c16;
        wc[nt]   = ((const float4*)(ws + WC4))[d];
        ba_r[nt] = ws[BA + d];
        gbr[nt]  = ws[GB + d];
    }

    const int g0 = g * GPW;
    const int k3 = lane / 3, c3 = lane - k3 * 3;   // lane<48: (neighbor, component)

    // ---- preamble ----
    if (lane < 24) pxyz_s[lane] = pxyz[g0 * 3 + lane];
    float nv0 = (lane < 48) ? nxyz[(size_t)g0 * 48 + lane] : 0.f;
    if (lane < 48) dxyz[k3 * 4 + c3] = pxyz_s[c3] - nv0;   // point 0, buf 0

    // phig = pf@(Wphi@Wg) + gb for the 8 points (rows 0..7 of one MFMA pass)
    {
        float4 x0{}, x1{}, x2{}, x3{};
        if (c16 < 8) {
            const float* base = pfeat + (size_t)(g0 + c16) * 64 + quad * 8;
            x0 = *(const float4*)(base);
            x1 = *(const float4*)(base + 4);
            x2 = *(const float4*)(base + 32);
            x3 = *(const float4*)(base + 36);
        }
        Frag pa0, pa1;
        pa0.u[0] = pk(x0.x, x0.y); pa0.u[1] = pk(x0.z, x0.w);
        pa0.u[2] = pk(x1.x, x1.y); pa0.u[3] = pk(x1.z, x1.w);
        pa1.u[0] = pk(x2.x, x2.y); pa1.u[1] = pk(x2.z, x2.w);
        pa1.u[2] = pk(x3.x, x3.y); pa1.u[3] = pk(x3.z, x3.w);
        #pragma unroll
        for (int nt = 0; nt < 4; ++nt) {
            Frag b0, b1;
            b0.v = fr[1536 + (nt * 2 + 0) * 64 + lane];
            b1.v = fr[1536 + (nt * 2 + 1) * 64 + lane];
            f32x4 acc = {gbr[nt], gbr[nt], gbr[nt], gbr[nt]};
            acc = MFMA(pa0.s, b0.s, acc);
            acc = MFMA(pa1.s, b1.s, acc);
            if (quad < 2) {
                #pragma unroll
                for (int r = 0; r < 4; ++r)
                    phig_s[(quad * 4 + r) * 65 + nt * 16 + c16] = acc[r];
            }
        }
    }

    // nf prefetch for point 0 — DENSE pattern: per-lane 16B at c16*256 + quad*16,
    // bands {0,64,128,192}B. Each instruction's 64 lanes cover the point's 4KB
    // densely in 1KB windows -> every 32B sector fully covered -> 1x HBM fetch.
    // Lane (quad,c16) holds feature chunks quad*4..+3 of each 16-feature band.
    const float* nfb = nfeat + (size_t)g0 * (KNB * 64) + (size_t)c16 * 64 + quad * 4;
    float4 f0 = *(const float4*)(nfb);
    float4 f1 = *(const float4*)(nfb + 16);
    float4 f2 = *(const float4*)(nfb + 32);
    float4 f3 = *(const float4*)(nfb + 48);
    float nvn = (lane < 48) ? nxyz[(size_t)g0 * 48 + 48 + lane] : 0.f;

    // bpermute source addresses (byte = lane*4): frag lane (quad,c16) needs
    // feature chunks 2q,2q+1 which live in lanes ((quad&1)*2)*16+c16 and +16.
    const int s0 = ((((quad & 1) << 1) << 4) + c16) << 2;
    const int s1 = s0 + 64;

    #pragma unroll 1
    for (int i = 0; i < GPW; ++i) {
        const int n = g0 + i;

        // pack current point's dense chunks, then overwrite prefetch regs
        uint_t p0w0 = pk(f0.x, f0.y), p0w1 = pk(f0.z, f0.w);
        uint_t p1w0 = pk(f1.x, f1.y), p1w1 = pk(f1.z, f1.w);
        uint_t p2w0 = pk(f2.x, f2.y), p2w1 = pk(f2.z, f2.w);
        uint_t p3w0 = pk(f3.x, f3.y), p3w1 = pk(f3.z, f3.w);
        if (i + 1 < GPW) {
            const float* nf2 = nfb + (size_t)(i + 1) * (KNB * 64);
            f0 = *(const float4*)(nf2);
            f1 = *(const float4*)(nf2 + 16);
            f2 = *(const float4*)(nf2 + 32);
            f3 = *(const float4*)(nf2 + 48);
        }

        // in-register redistribution to A-frags (16 bpermutes, conflict-free)
        Frag na0, na1;
        {
            uint_t a, b;
            a = bperm(s0, p0w0); b = bperm(s0, p1w0); na0.u[0] = (quad < 2) ? a : b;
            a = bperm(s0, p0w1); b = bperm(s0, p1w1); na0.u[1] = (quad < 2) ? a : b;
            a = bperm(s1, p0w0); b = bperm(s1, p1w0); na0.u[2] = (quad < 2) ? a : b;
            a = bperm(s1, p0w1); b = bperm(s1, p1w1); na0.u[3] = (quad < 2) ? a : b;
            a = bperm(s0, p2w0); b = bperm(s0, p3w0); na1.u[0] = (quad < 2) ? a : b;
            a = bperm(s0, p2w1); b = bperm(s0, p3w1); na1.u[1] = (quad < 2) ? a : b;
            a = bperm(s1, p2w0); b = bperm(s1, p3w0); na1.u[2] = (quad < 2) ? a : b;
            a = bperm(s1, p2w1); b = bperm(s1, p3w1); na1.u[3] = (quad < 2) ? a : b;
        }

        // early LDS reads: phig values, this point's dxyz rows
        float ph[4];
        #pragma unroll
        for (int nt = 0; nt < 4; ++nt) ph[nt] = phig_s[i * 65 + nt * 16 + c16];
        float4 dd[4];
        #pragma unroll
        for (int r = 0; r < 4; ++r)
            dd[r] = ((const float4*)dxyz)[(i & 1) * 16 + quad * 4 + r];

        // write next point's dxyz (uses prefetched nvn), then prefetch nxyz i+2
        if (i + 1 < GPW) {
            if (lane < 48)
                dxyz[((i + 1) & 1) * 64 + k3 * 4 + c3] = pxyz_s[(i + 1) * 3 + c3] - nvn;
            if (i + 2 < GPW)
                nvn = (lane < 48) ? nxyz[((size_t)n + 2) * 48 + lane] : 0.f;
        }

        // u = diff@Wc + bc, relu -> delta in C-layout; pack transpose into utr
        float d_c[4][4];
        #pragma unroll
        for (int nt = 0; nt < 4; ++nt) {
            #pragma unroll
            for (int r = 0; r < 4; ++r) {
                float u = fmaf(dd[r].x, wc[nt].x,
                          fmaf(dd[r].y, wc[nt].y,
                          fmaf(dd[r].z, wc[nt].z, wc[nt].w)));
                d_c[nt][r] = fmaxf(u, 0.f);
            }
        }
        #pragma unroll
        for (int r = 0; r < 4; ++r) {
            int row = (quad * 4 + r) * 34;
            utr[row + c16]      = pk(d_c[0][r], d_c[1][r]);
            utr[row + 16 + c16] = pk(d_c[2][r], d_c[3][r]);
        }

        // alpha = nf@Wa + ba (delta added after); overlaps utr write latency
        f32x4 aacc[4];
        #pragma unroll
        for (int nt = 0; nt < 4; ++nt) {
            aacc[nt] = f32x4{ba_r[nt], ba_r[nt], ba_r[nt], ba_r[nt]};
            aacc[nt] = MFMA(na0.s, wa[nt * 2 + 0].s, aacc[nt]);
            aacc[nt] = MFMA(na1.s, wa[nt * 2 + 1].s, aacc[nt]);
        }
        // gamma = phig - nf@WpsiG ...
        f32x4 gacc[4];
        #pragma unroll
        for (int nt = 0; nt < 4; ++nt) {
            gacc[nt] = f32x4{ph[nt], ph[nt], ph[nt], ph[nt]};
            gacc[nt] = MFMA(na0.s, wpsig[nt * 2 + 0].s, gacc[nt]);
            gacc[nt] = MFMA(na1.s, wpsig[nt * 2 + 1].s, gacc[nt]);
        }
        // ... + delta@Wg (read back transposed delta as ready-made A-frags)
        Frag da0, da1;
        {
            const uint_t* rowp = utr + c16 * 34 + quad * 4;
            uint2 a = *(const uint2*)(rowp);
            uint2 b = *(const uint2*)(rowp + 2);
            uint2 c = *(const uint2*)(rowp + 16);
            uint2 d = *(const uint2*)(rowp + 18);
            da0.u[0] = a.x; da0.u[1] = a.y; da0.u[2] = b.x; da0.u[3] = b.y;
            da1.u[0] = c.x; da1.u[1] = c.y; da1.u[2] = d.x; da1.u[3] = d.y;
        }
        #pragma unroll
        for (int nt = 0; nt < 4; ++nt) {
            gacc[nt] = MFMA(da0.s, wg[nt * 2 + 0].s, gacc[nt]);
            gacc[nt] = MFMA(da1.s, wg[nt * 2 + 1].s, gacc[nt]);
        }
        // alpha finalize
        #pragma unroll
        for (int nt = 0; nt < 4; ++nt)
            #pragma unroll
            for (int r = 0; r < 4; ++r) aacc[nt][r] += d_c[nt][r];

        // softmax over features (no max-sub: |gamma| small by construction)
        float e[4][4], smi[4];
        #pragma unroll
        for (int r = 0; r < 4; ++r) {
            float s = 0.f;
            #pragma unroll
            for (int nt = 0; nt < 4; ++nt) { e[nt][r] = __expf(gacc[nt][r]); s += e[nt][r]; }
            #pragma unroll
            for (int d2 = 1; d2 < 16; d2 <<= 1) s += __shfl_xor(s, d2);
            smi[r] = __builtin_amdgcn_rcpf(s);
        }
        // out_d = sum_k rho*alpha
        float p0 = 0.f, p1 = 0.f, p2 = 0.f, p3 = 0.f;
        #pragma unroll
        for (int r = 0; r < 4; ++r) {
            p0 = fmaf(e[0][r] * smi[r], aacc[0][r], p0);
            p1 = fmaf(e[1][r] * smi[r], aacc[1][r], p1);
            p2 = fmaf(e[2][r] * smi[r], aacc[2][r], p2);
            p3 = fmaf(e[3][r] * smi[r], aacc[3][r], p3);
        }
        p0 += __shfl_xor(p0, 16); p0 += __shfl_xor(p0, 32);
        p1 += __shfl_xor(p1, 16); p1 += __shfl_xor(p1, 32);
        p2 += __shfl_xor(p2, 16); p2 += __shfl_xor(p2, 32);
        p3 += __shfl_xor(p3, 16); p3 += __shfl_xor(p3, 32);
        float sel = (quad == 0) ? p0 : (quad == 1) ? p1 : (quad == 2) ? p2 : p3;
        obuf[i * 64 + lane] = sel;                 // buffer; wide store after loop
    }

    // one contiguous 2 KB store per wave, 32B per lane (true-size write counting)
    float4 o0 = ((const float4*)obuf)[lane * 2];
    float4 o1 = ((const float4*)obuf)[lane * 2 + 1];
    float4* og = (float4*)(out + (size_t)g0 * 64);
    og[lane * 2]     = o0;
    og[lane * 2 + 1] = o1;
}

extern "C" void kernel_launch(void* const* d_in, const int* in_sizes, int n_in,
                              void* d_out, int out_size, void* d_ws, size_t ws_size,
                              hipStream_t stream) {
    const float* pxyz  = (const float*)d_in[0];
    const float* pfeat = (const float*)d_in[1];
    const float* nxyz  = (const float*)d_in[2];
    const float* nfeat = (const float*)d_in[3];
    const float* Wphi  = (const float*)d_in[4];
    const float* bphi  = (const float*)d_in[5];
    const float* Wpsi  = (const float*)d_in[6];
    const float* bpsi  = (const float*)d_in[7];
    const float* Wa    = (const float*)d_in[8];
    const float* ba    = (const float*)d_in[9];
    const float* Wg    = (const float*)d_in[10];
    const float* bg    = (const float*)d_in[11];
    const float* Wd1   = (const float*)d_in[12];
    const float* bd1   = (const float*)d_in[13];
    const float* Wd2   = (const float*)d_in[14];
    const float* bd2   = (const float*)d_in[15];
    float* ws = (float*)d_ws;

    pt_prep<<<33, 256, 0, stream>>>(Wphi, bphi, Wpsi, bpsi, Wa, ba, Wg, bg,
                                    Wd1, bd1, Wd2, bd2, ws);
    pt_main<<<NBLOCKS, 256, 0, stream>>>(pxyz, pfeat, nxyz, nfeat, ws, (float*)d_out);
}